// Round 4
// baseline (376.176 us; speedup 1.0000x reference)
//
#include <hip/hip_runtime.h>
#include <hip/hip_bf16.h>

#define NFEAT 128
#define HID 256
#define BN_EPS 1e-5f
#define NBIN 64  // stats replica bins (atomic de-contention)

typedef __attribute__((ext_vector_type(8))) __bf16 bf16x8;
typedef __attribute__((ext_vector_type(4))) float f32x4;

static __device__ __forceinline__ float bflo(unsigned u) {
    union { unsigned x; float f; } c; c.x = u << 16; return c.f;
}
static __device__ __forceinline__ float bfhi(unsigned u) {
    union { unsigned x; float f; } c; c.x = u & 0xffff0000u; return c.f;
}

// ---------- CSR build ----------
__global__ void k_count(const int* __restrict__ ei, int E, int* __restrict__ cnt,
                        int* __restrict__ rank) {
    int e = blockIdx.x * blockDim.x + threadIdx.x;
    if (e < E) rank[e] = atomicAdd(&cnt[ei[E + e]], 1);
}

__global__ void k_scan1(const int* __restrict__ cnt, int n, int* __restrict__ partial,
                        int* __restrict__ blk_total) {
    __shared__ int sh[256];
    int i = blockIdx.x * 256 + threadIdx.x;
    int v = (i < n) ? cnt[i] : 0;
    sh[threadIdx.x] = v;
    __syncthreads();
    for (int off = 1; off < 256; off <<= 1) {
        int x = (threadIdx.x >= off) ? sh[threadIdx.x - off] : 0;
        __syncthreads();
        sh[threadIdx.x] += x;
        __syncthreads();
    }
    if (i < n) partial[i] = sh[threadIdx.x] - v;
    if (threadIdx.x == 255) blk_total[blockIdx.x] = sh[255];
}

__global__ void k_scan2(int* __restrict__ blk, int nb) {
    __shared__ int sh[256];
    int t = threadIdx.x;
    int v = (t < nb) ? blk[t] : 0;
    sh[t] = v;
    __syncthreads();
    for (int off = 1; off < 256; off <<= 1) {
        int x = (t >= off) ? sh[t - off] : 0;
        __syncthreads();
        sh[t] += x;
        __syncthreads();
    }
    if (t < nb) blk[t] = sh[t] - v;
}

__global__ void k_finalize(const int* __restrict__ partial, const int* __restrict__ blk,
                           const int* __restrict__ cnt, int n, int* __restrict__ row_start,
                           float* __restrict__ dinv) {
    int i = blockIdx.x * blockDim.x + threadIdx.x;
    if (i < n) {
        row_start[i] = partial[i] + blk[i >> 8];
        dinv[i] = rsqrtf((float)(cnt[i] + 1));
    }
}

__global__ void k_fill(const int* __restrict__ ei, const int* __restrict__ rank,
                       const int* __restrict__ row_start, int E, int* __restrict__ col) {
    int e = blockIdx.x * blockDim.x + threadIdx.x;
    if (e < E) {
        int d = ei[E + e];
        col[row_start[d] + rank[e]] = ei[e];
    }
}

// ---------- r = A_hat * 1  (r_i = dinv_i*(dinv_i + sum_j dinv_j)) ----------
__global__ __launch_bounds__(256) void k_rvec(const int* __restrict__ rs,
                                              const int* __restrict__ rc,
                                              const int* __restrict__ col,
                                              const float* __restrict__ dinv,
                                              float* __restrict__ r, int N) {
    const int wid = blockIdx.x * 4 + (threadIdx.x >> 6);
    if (wid >= N) return;
    const int lane = threadIdx.x & 63;
    const int s = rs[wid];
    const int deg = rc[wid];
    float acc = 0.f;
    for (int e = lane; e < deg; e += 64) acc += dinv[col[s + e]];
#pragma unroll
    for (int m = 1; m < 64; m <<= 1) acc += __shfl_xor(acc, m);
    if (lane == 0) {
        float di = dinv[wid];
        r[wid] = di * (di + acc);
    }
}

// ---------- fp32 -> bf16 cast with per-row dinv scale ----------
__global__ void k_scale_cast(const float* __restrict__ in, const float* __restrict__ dinv,
                             __hip_bfloat16* __restrict__ out, int shift, int n4) {
    int i = blockIdx.x * blockDim.x + threadIdx.x;
    if (i < n4) {
        float d = dinv[i >> shift];
        float4 v = *(const float4*)(in + (size_t)i * 4);
        __hip_bfloat16* o = out + (size_t)i * 4;
        o[0] = __float2bfloat16(v.x * d);
        o[1] = __float2bfloat16(v.y * d);
        o[2] = __float2bfloat16(v.z * d);
        o[3] = __float2bfloat16(v.w * d);
    }
}

// ---------- weight transposes (W1 -> Wt1 [256][128], Wfc -> Wtf [256][256]) ----------
__global__ void k_transpose2(const float* __restrict__ W1, const float* __restrict__ Wf,
                             __hip_bfloat16* __restrict__ Wt1, __hip_bfloat16* __restrict__ Wtf) {
    int idx = blockIdx.x * 256 + threadIdx.x;
    if (idx < 32768) {
        int n = idx & 255;           // out channel
        int k = idx >> 8;            // 0..127
        Wt1[n * 128 + k] = __float2bfloat16(W1[k * 256 + n]);
    } else {
        int base = idx - 32768;      // 0..65535
        int n = base & 255;
        int k = base >> 8;           // 0..255
        Wtf[n * 256 + k] = __float2bfloat16(Wf[k * 256 + n]);
    }
}

// ---------- BN affine fold over NBIN replica bins ----------
__global__ void k_bnfold(const float* __restrict__ gs, const float* __restrict__ g,
                         const float* __restrict__ be, const float* __restrict__ b, float invN,
                         float* __restrict__ sc, float* __restrict__ bv) {
    int c = threadIdx.x;
    float s = 0.f, q = 0.f;
    for (int r = 0; r < NBIN; r++) {
        s += gs[r * 512 + c];
        q += gs[r * 512 + 256 + c];
    }
    float mean = s * invN;
    float var = q * invN - mean * mean;
    float scl = rsqrtf(var + BN_EPS) * g[c];
    float bb = b ? b[c] : 0.f;
    sc[c] = scl;
    bv[c] = (bb - mean) * scl + be[c];
}

// ---------- folded weight: WfT[n][k] = sum_m W1[k][m]*sc[m]*W2[m][n]  (Bt layout, bf16) ----------
__global__ __launch_bounds__(256) void k_foldW(const float* __restrict__ W1,
                                               const float* __restrict__ W2,
                                               const float* __restrict__ sc,
                                               __hip_bfloat16* __restrict__ WfT) {
    int k = blockIdx.x;    // 0..127
    int n = threadIdx.x;   // 0..255
    float acc = 0.f;
    for (int m = 0; m < 256; m++) acc += W1[k * 256 + m] * sc[m] * W2[m * 256 + n];
    WfT[(size_t)n * 128 + k] = __float2bfloat16(acc);
}

// ---------- u[n] = sum_m W2[m][n] * bv[m] ----------
__global__ void k_uvec(const float* __restrict__ W2, const float* __restrict__ bv,
                       float* __restrict__ u) {
    int n = threadIdx.x;
    float acc = 0.f;
    for (int m = 0; m < 256; m++) acc += W2[m * 256 + n] * bv[m];
    u[n] = acc;
}

// ---------- wave-per-node pure-add SpMM on pre-scaled rows ----------
template <int PL>
static __device__ __forceinline__ void loadrow(const __hip_bfloat16* p, float* v) {
    if constexpr (PL == 4) {
        uint2 u = *(const uint2*)p;
        v[0] = bflo(u.x); v[1] = bfhi(u.x); v[2] = bflo(u.y); v[3] = bfhi(u.y);
    } else {
        unsigned u = *(const unsigned*)p;
        v[0] = bflo(u); v[1] = bfhi(u);
    }
}

template <int C>
__global__ __launch_bounds__(256) void k_spmm_w(const __hip_bfloat16* __restrict__ Hs,
                                                const int* __restrict__ rs,
                                                const int* __restrict__ rc,
                                                const int* __restrict__ col,
                                                const float* __restrict__ dinv,
                                                __hip_bfloat16* __restrict__ out,
                                                __hip_bfloat16* __restrict__ out2, int N) {
    constexpr int PL = C / 64;
    const int wid = blockIdx.x * 4 + (threadIdx.x >> 6);
    if (wid >= N) return;
    const int lane = threadIdx.x & 63;
    const int ch = lane * PL;
    const int s = rs[wid];
    const int deg = rc[wid];
    const float di = dinv[wid];

    float acc[PL];
    loadrow<PL>(Hs + (size_t)wid * C + ch, acc);  // self-loop term

    int e = 0;
    for (; e + 8 <= deg; e += 8) {
        int idx[8];
#pragma unroll
        for (int j = 0; j < 8; j++) idx[j] = col[s + e + j];
        float v[8][PL];
#pragma unroll
        for (int j = 0; j < 8; j++) loadrow<PL>(Hs + (size_t)idx[j] * C + ch, v[j]);
#pragma unroll
        for (int j = 0; j < 8; j++)
#pragma unroll
            for (int i = 0; i < PL; i++) acc[i] += v[j][i];
    }
    for (; e < deg; e++) {
        int i0 = col[s + e];
        float v0[PL];
        loadrow<PL>(Hs + (size_t)i0 * C + ch, v0);
#pragma unroll
        for (int i = 0; i < PL; i++) acc[i] += v0[i];
    }
    union { unsigned u[PL / 2]; unsigned short us[PL]; } o;
#pragma unroll
    for (int i = 0; i < PL; i++) {
        __hip_bfloat16 b = __float2bfloat16(di * acc[i]);
        o.us[i] = *(unsigned short*)&b;
    }
    if constexpr (PL == 4)
        *(uint2*)(out + (size_t)wid * C + ch) = *(uint2*)o.u;
    else
        *(unsigned*)(out + (size_t)wid * C + ch) = o.u[0];
    if (out2) {  // dinv-prescaled copy for the next aggregation pass
        union { unsigned u[PL / 2]; unsigned short us[PL]; } o2;
        float d2 = di * di;
#pragma unroll
        for (int i = 0; i < PL; i++) {
            __hip_bfloat16 b = __float2bfloat16(d2 * acc[i]);
            o2.us[i] = *(unsigned short*)&b;
        }
        if constexpr (PL == 4)
            *(uint2*)(out2 + (size_t)wid * C + ch) = *(uint2*)o2.u;
        else
            *(unsigned*)(out2 + (size_t)wid * C + ch) = o2.u[0];
    }
}

// ---------- single-barrier MFMA GEMM, 128-row tile ----------
// out[M][256] = A[M][K] @ B[K][256] (+bias) (+ rank-1 rvec*uvec^T) ; optional BN affine on A;
// optional bf16/fp32 out; optional fused BN stats (atomics into NBIN replica bins).
// Block = 128 rows x 128 cols, grid (ceil(M/128), 2). Each wave owns rows wv*32..+31 as
// TWO 16-row m-tiles sharing each B fragment read (halves LDS read traffic, 16 indep
// accumulator chains for MFMA ILP). B slice staged once, ONE barrier before epilogue.
// NOTE: last block reads A rows >= M (buffers padded by 128; results discarded by guard).
template <int K>
__global__ __launch_bounds__(256) void k_gemm2(const __hip_bfloat16* __restrict__ A,
                                               const __hip_bfloat16* __restrict__ Bt,
                                               const float* __restrict__ bias,
                                               __hip_bfloat16* __restrict__ outb,
                                               float* __restrict__ outf,
                                               float* __restrict__ gs,
                                               const float* __restrict__ rvec,
                                               const float* __restrict__ uvec,
                                               const float* __restrict__ bnsc,
                                               const float* __restrict__ bnof, int M) {
    constexpr int KS = K / 32;       // MFMA k-steps
    constexpr int LDR = K + 8;       // LDS row stride (elems): +16B pad -> <=2-way read alias
    constexpr int ROWU4 = K / 8;     // uint4 per B row
    __shared__ __align__(16) unsigned short Bs[128 * LDR];
    __shared__ float sred[4][128];
    __shared__ float qred[4][128];

    const int t = threadIdx.x;
    const int wv = t >> 6;
    const int lane = t & 63;
    const int mlane = lane & 15;
    const int quad = lane >> 4;
    const int m0 = blockIdx.x * 128;
    const int n0 = blockIdx.y * 128;

    // A fragments: wave wv covers rows m0+wv*32 .. +31 (two 16-row m-tiles)
    bf16x8 a[2][KS];
#pragma unroll
    for (int mt = 0; mt < 2; mt++) {
        const int arow = m0 + wv * 32 + mt * 16 + mlane;
#pragma unroll
        for (int ks = 0; ks < KS; ks++) {
            bf16x8 raw = *(const bf16x8*)(A + (size_t)arow * K + ks * 32 + quad * 8);
            if (bnsc) {  // BN affine applied in-register (pre-MFMA), channel = ks*32+quad*8+j
                int cb = ks * 32 + quad * 8;
                union { bf16x8 v; unsigned u[4]; } cu; cu.v = raw;
                union { unsigned u[4]; unsigned short us[8]; } ou;
#pragma unroll
                for (int j = 0; j < 4; j++) {
                    float lo = bflo(cu.u[j]) * bnsc[cb + 2 * j] + bnof[cb + 2 * j];
                    float hi = bfhi(cu.u[j]) * bnsc[cb + 2 * j + 1] + bnof[cb + 2 * j + 1];
                    __hip_bfloat16 bl = __float2bfloat16(lo);
                    __hip_bfloat16 bh = __float2bfloat16(hi);
                    ou.us[2 * j] = *(unsigned short*)&bl;
                    ou.us[2 * j + 1] = *(unsigned short*)&bh;
                }
                a[mt][ks] = *(bf16x8*)ou.u;
            } else {
                a[mt][ks] = raw;
            }
        }
    }

    // stage B slice: Bt[n0..n0+128][0..K] -> Bs (coalesced, all 16B loads in flight)
#pragma unroll
    for (int i = 0; i < 128 * ROWU4 / 256; i++) {
        int idx = t + i * 256;
        int row = idx / ROWU4;
        int c = idx % ROWU4;
        uint4 v = *(const uint4*)(Bt + (size_t)(n0 + row) * K + c * 8);
        *(uint4*)(Bs + row * LDR + c * 8) = v;
    }
    __syncthreads();  // the ONLY barrier before the epilogue

    f32x4 acc[2][8];
#pragma unroll
    for (int mt = 0; mt < 2; mt++)
#pragma unroll
        for (int i = 0; i < 8; i++) acc[mt][i] = (f32x4){0.f, 0.f, 0.f, 0.f};

#pragma unroll
    for (int nt = 0; nt < 8; nt++) {
        const unsigned short* bp = Bs + (nt * 16 + mlane) * LDR + quad * 8;
#pragma unroll
        for (int ks = 0; ks < KS; ks++) {
            bf16x8 b = *(const bf16x8*)(bp + ks * 32);  // one LDS read feeds two MFMAs
            acc[0][nt] = __builtin_amdgcn_mfma_f32_16x16x32_bf16(a[0][ks], b, acc[0][nt], 0, 0, 0);
            acc[1][nt] = __builtin_amdgcn_mfma_f32_16x16x32_bf16(a[1][ks], b, acc[1][nt], 0, 0, 0);
        }
    }

    // C/D mapping: col = lane&15, row = quad*4 + reg
    float rv[2][4] = {{0.f, 0.f, 0.f, 0.f}, {0.f, 0.f, 0.f, 0.f}};
    if (rvec) {
#pragma unroll
        for (int mt = 0; mt < 2; mt++)
#pragma unroll
            for (int r = 0; r < 4; r++) {
                int row = m0 + wv * 32 + mt * 16 + quad * 4 + r;
                if (row < M) rv[mt][r] = rvec[row];
            }
    }
    float sp[8], qp[8];
#pragma unroll
    for (int nt = 0; nt < 8; nt++) {
        int colx = n0 + nt * 16 + mlane;
        float bv = bias[colx];
        float uvn = uvec ? uvec[colx] : 0.f;
        float s = 0.f, q = 0.f;
#pragma unroll
        for (int mt = 0; mt < 2; mt++)
#pragma unroll
            for (int r = 0; r < 4; r++) {
                int row = m0 + wv * 32 + mt * 16 + quad * 4 + r;
                if (row < M) {
                    float h = acc[mt][nt][r] + bv + rv[mt][r] * uvn;
                    if (outb) outb[(size_t)row * HID + colx] = __float2bfloat16(h);
                    if (outf) outf[(size_t)row * HID + colx] = h;
                    s += h;
                    q += h * h;
                }
            }
        sp[nt] = s;
        qp[nt] = q;
    }
    if (gs) {
#pragma unroll
        for (int nt = 0; nt < 8; nt++) {
            sp[nt] += __shfl_xor(sp[nt], 16);
            sp[nt] += __shfl_xor(sp[nt], 32);
            qp[nt] += __shfl_xor(qp[nt], 16);
            qp[nt] += __shfl_xor(qp[nt], 32);
        }
        if (quad == 0) {
#pragma unroll
            for (int nt = 0; nt < 8; nt++) {
                sred[wv][nt * 16 + mlane] = sp[nt];
                qred[wv][nt * 16 + mlane] = qp[nt];
            }
        }
        __syncthreads();
        if (t < 128) {
            float ss = sred[0][t] + sred[1][t] + sred[2][t] + sred[3][t];
            float qq = qred[0][t] + qred[1][t] + qred[2][t] + qred[3][t];
            float* bin = gs + (blockIdx.x & (NBIN - 1)) * 512;  // de-contended replicas
            atomicAdd(&bin[n0 + t], ss);
            atomicAdd(&bin[256 + n0 + t], qq);
        }
    }
}

extern "C" void kernel_launch(void* const* d_in, const int* in_sizes, int n_in, void* d_out,
                              int out_size, void* d_ws, size_t ws_size, hipStream_t stream) {
    const float* x = (const float*)d_in[0];
    const int* ei = (const int*)d_in[1];
    const float* W1 = (const float*)d_in[2];
    const float* b1 = (const float*)d_in[3];
    const float* g1 = (const float*)d_in[4];
    const float* be1 = (const float*)d_in[5];
    const float* W2 = (const float*)d_in[6];
    const float* b2 = (const float*)d_in[7];
    const float* g2 = (const float*)d_in[8];
    const float* be2 = (const float*)d_in[9];
    const float* Wfc = (const float*)d_in[10];
    const float* bfc = (const float*)d_in[11];
    float* out = (float*)d_out;

    const int N = in_sizes[0] / NFEAT;  // 50000
    const int E = in_sizes[1] / 2;      // 800000
    const float invN = 1.0f / (float)N;

    char* ws = (char*)d_ws;
    size_t off = 0;
    auto alloc = [&](size_t bytes) -> void* {
        void* p = ws + off;
        off += (bytes + 255) & ~(size_t)255;
        return p;
    };
    int* row_cnt = (int*)alloc((size_t)N * 4);
    int* partial = (int*)alloc((size_t)N * 4);
    int* row_start = (int*)alloc((size_t)N * 4);
    int* blk = (int*)alloc(256 * 4);
    float* dinv = (float*)alloc((size_t)N * 4);
    int* rank = (int*)alloc((size_t)E * 4);
    int* col_idx = (int*)alloc((size_t)E * 4);
    float* gs1 = (float*)alloc((size_t)NBIN * 512 * 4);  // gs2 contiguous after
    float* gs2 = (float*)alloc((size_t)NBIN * 512 * 4);
    float* sc1 = (float*)alloc(256 * 4);
    float* bv1 = (float*)alloc(256 * 4);
    float* uvec = (float*)alloc(256 * 4);
    float* sc2 = (float*)alloc(256 * 4);
    float* of2 = (float*)alloc(256 * 4);
    float* rvec = (float*)alloc((size_t)(N + 128) * 4);
    __hip_bfloat16* Wt1 = (__hip_bfloat16*)alloc(256 * 128 * 2);
    __hip_bfloat16* Wtf = (__hip_bfloat16*)alloc(256 * 256 * 2);
    __hip_bfloat16* WfT = (__hip_bfloat16*)alloc(256 * 128 * 2);
    // node buffers padded by 128 rows (GEMM A-fragment overread of last 128-row block)
    __hip_bfloat16* xs = (__hip_bfloat16*)alloc((size_t)(N + 128) * NFEAT * 2);
    __hip_bfloat16* aggX = (__hip_bfloat16*)alloc((size_t)(N + 128) * NFEAT * 2);
    __hip_bfloat16* t1s = (__hip_bfloat16*)alloc((size_t)(N + 128) * NFEAT * 2);
    __hip_bfloat16* h2 = (__hip_bfloat16*)alloc((size_t)(N + 128) * HID * 2);
    __hip_bfloat16* t2 = xs;  // xs dead after spmm1

    hipMemsetAsync(row_cnt, 0, (size_t)N * 4, stream);
    hipMemsetAsync(gs1, 0, (size_t)NBIN * 512 * 4 * 2, stream);  // gs1 + gs2 (contiguous)

    // CSR build
    k_count<<<(E + 255) / 256, 256, 0, stream>>>(ei, E, row_cnt, rank);
    int nblk = (N + 255) / 256;
    k_scan1<<<nblk, 256, 0, stream>>>(row_cnt, N, partial, blk);
    k_scan2<<<1, 256, 0, stream>>>(blk, nblk);
    k_finalize<<<nblk, 256, 0, stream>>>(partial, blk, row_cnt, N, row_start, dinv);
    k_fill<<<(E + 255) / 256, 256, 0, stream>>>(ei, rank, row_start, E, col_idx);

    k_transpose2<<<384, 256, 0, stream>>>(W1, Wfc, Wt1, Wtf);

    // xs = dinv_row * x (bf16); shift = log2(128/4) = 5
    k_scale_cast<<<(N * NFEAT / 4 + 255) / 256, 256, 0, stream>>>(x, dinv, xs, 5, N * NFEAT / 4);

    int sg = (N + 3) / 4;
    k_rvec<<<sg, 256, 0, stream>>>(row_start, row_cnt, col_idx, dinv, rvec, N);

    dim3 gg((N + 127) / 128, 2);
    // t1 = A_hat * x : aggX (plain) + t1s (dinv-prescaled for pass 2)
    k_spmm_w<NFEAT><<<sg, 256, 0, stream>>>(xs, row_start, row_cnt, col_idx, dinv, aggX, t1s, N);
    // BN1 stats only: h1 = aggX@W1 + b1 (never materialized)
    k_gemm2<NFEAT><<<gg, 256, 0, stream>>>(aggX, Wt1, b1, nullptr, nullptr, gs1,
                                           nullptr, nullptr, nullptr, nullptr, N);
    k_bnfold<<<1, 256, 0, stream>>>(gs1, g1, be1, b1, invN, sc1, bv1);
    k_foldW<<<128, 256, 0, stream>>>(W1, W2, sc1, WfT);
    k_uvec<<<1, 256, 0, stream>>>(W2, bv1, uvec);
    // t2 = A_hat * t1 (128-ch aggregation replaces the old 256-ch one)
    k_spmm_w<NFEAT><<<sg, 256, 0, stream>>>(t1s, row_start, row_cnt, col_idx, dinv, t2, nullptr, N);
    // h2pre = t2 @ (W1*diag(sc1)*W2) + rvec*uvec^T + b2, fused BN2 stats
    k_gemm2<NFEAT><<<gg, 256, 0, stream>>>(t2, WfT, b2, h2, nullptr, gs2,
                                           rvec, uvec, nullptr, nullptr, N);
    k_bnfold<<<1, 256, 0, stream>>>(gs2, g2, be2, nullptr, invN, sc2, of2);
    // out = BN2(h2pre) @ Wfc + bfc ; BN2 affine folded into A-load
    k_gemm2<HID><<<gg, 256, 0, stream>>>(h2, Wtf, bfc, nullptr, out, nullptr,
                                         nullptr, nullptr, sc2, of2, N);
}

// Round 5
// 347.592 us; speedup vs baseline: 1.0822x; 1.0822x over previous
//
#include <hip/hip_runtime.h>
#include <hip/hip_bf16.h>

#define NFEAT 128
#define HID 256
#define BN_EPS 1e-5f
#define NBIN 64  // stats replica bins (atomic de-contention)

typedef __attribute__((ext_vector_type(8))) __bf16 bf16x8;
typedef __attribute__((ext_vector_type(4))) float f32x4;

static __device__ __forceinline__ float bflo(unsigned u) {
    union { unsigned x; float f; } c; c.x = u << 16; return c.f;
}
static __device__ __forceinline__ float bfhi(unsigned u) {
    union { unsigned x; float f; } c; c.x = u & 0xffff0000u; return c.f;
}

// ---------- CSR build ----------
__global__ void k_count(const int* __restrict__ ei, int E, int* __restrict__ cnt,
                        int* __restrict__ rank) {
    int e = blockIdx.x * blockDim.x + threadIdx.x;
    if (e < E) rank[e] = atomicAdd(&cnt[ei[E + e]], 1);
}

__global__ void k_scan1(const int* __restrict__ cnt, int n, int* __restrict__ partial,
                        int* __restrict__ blk_total) {
    __shared__ int sh[256];
    int i = blockIdx.x * 256 + threadIdx.x;
    int v = (i < n) ? cnt[i] : 0;
    sh[threadIdx.x] = v;
    __syncthreads();
    for (int off = 1; off < 256; off <<= 1) {
        int x = (threadIdx.x >= off) ? sh[threadIdx.x - off] : 0;
        __syncthreads();
        sh[threadIdx.x] += x;
        __syncthreads();
    }
    if (i < n) partial[i] = sh[threadIdx.x] - v;
    if (threadIdx.x == 255) blk_total[blockIdx.x] = sh[255];
}

__global__ void k_scan2(int* __restrict__ blk, int nb) {
    __shared__ int sh[256];
    int t = threadIdx.x;
    int v = (t < nb) ? blk[t] : 0;
    sh[t] = v;
    __syncthreads();
    for (int off = 1; off < 256; off <<= 1) {
        int x = (t >= off) ? sh[t - off] : 0;
        __syncthreads();
        sh[t] += x;
        __syncthreads();
    }
    if (t < nb) blk[t] = sh[t] - v;
}

__global__ void k_finalize(const int* __restrict__ partial, const int* __restrict__ blk,
                           const int* __restrict__ cnt, int n, int* __restrict__ row_start,
                           float* __restrict__ dinv) {
    int i = blockIdx.x * blockDim.x + threadIdx.x;
    if (i < n) {
        row_start[i] = partial[i] + blk[i >> 8];
        dinv[i] = rsqrtf((float)(cnt[i] + 1));
    }
}

__global__ void k_fill(const int* __restrict__ ei, const int* __restrict__ rank,
                       const int* __restrict__ row_start, int E, int* __restrict__ col) {
    int e = blockIdx.x * blockDim.x + threadIdx.x;
    if (e < E) {
        int d = ei[E + e];
        col[row_start[d] + rank[e]] = ei[e];
    }
}

// ---------- r = A_hat * 1  (r_i = dinv_i*(dinv_i + sum_j dinv_j)) ----------
__global__ __launch_bounds__(256) void k_rvec(const int* __restrict__ rs,
                                              const int* __restrict__ rc,
                                              const int* __restrict__ col,
                                              const float* __restrict__ dinv,
                                              float* __restrict__ r, int N) {
    const int wid = blockIdx.x * 4 + (threadIdx.x >> 6);
    if (wid >= N) return;
    const int lane = threadIdx.x & 63;
    const int s = rs[wid];
    const int deg = rc[wid];
    float acc = 0.f;
    for (int e = lane; e < deg; e += 64) acc += dinv[col[s + e]];
#pragma unroll
    for (int m = 1; m < 64; m <<= 1) acc += __shfl_xor(acc, m);
    if (lane == 0) {
        float di = dinv[wid];
        r[wid] = di * (di + acc);
    }
}

// ---------- fp32 -> bf16 cast with per-row dinv scale ----------
__global__ void k_scale_cast(const float* __restrict__ in, const float* __restrict__ dinv,
                             __hip_bfloat16* __restrict__ out, int shift, int n4) {
    int i = blockIdx.x * blockDim.x + threadIdx.x;
    if (i < n4) {
        float d = dinv[i >> shift];
        float4 v = *(const float4*)(in + (size_t)i * 4);
        __hip_bfloat16* o = out + (size_t)i * 4;
        o[0] = __float2bfloat16(v.x * d);
        o[1] = __float2bfloat16(v.y * d);
        o[2] = __float2bfloat16(v.z * d);
        o[3] = __float2bfloat16(v.w * d);
    }
}

// ---------- weight transposes (W1 -> Wt1 [256][128], Wfc -> Wtf [256][256]) ----------
__global__ void k_transpose2(const float* __restrict__ W1, const float* __restrict__ Wf,
                             __hip_bfloat16* __restrict__ Wt1, __hip_bfloat16* __restrict__ Wtf) {
    int idx = blockIdx.x * 256 + threadIdx.x;
    if (idx < 32768) {
        int n = idx & 255;           // out channel
        int k = idx >> 8;            // 0..127
        Wt1[n * 128 + k] = __float2bfloat16(W1[k * 256 + n]);
    } else {
        int base = idx - 32768;      // 0..65535
        int n = base & 255;
        int k = base >> 8;           // 0..255
        Wtf[n * 256 + k] = __float2bfloat16(Wf[k * 256 + n]);
    }
}

// ---------- BN affine fold over NBIN replica bins ----------
__global__ void k_bnfold(const float* __restrict__ gs, const float* __restrict__ g,
                         const float* __restrict__ be, const float* __restrict__ b, float invN,
                         float* __restrict__ sc, float* __restrict__ bv) {
    int c = threadIdx.x;
    float s = 0.f, q = 0.f;
    for (int r = 0; r < NBIN; r++) {
        s += gs[r * 512 + c];
        q += gs[r * 512 + 256 + c];
    }
    float mean = s * invN;
    float var = q * invN - mean * mean;
    float scl = rsqrtf(var + BN_EPS) * g[c];
    float bb = b ? b[c] : 0.f;
    sc[c] = scl;
    bv[c] = (bb - mean) * scl + be[c];
}

// ---------- folded weight: WfT[n][k] = sum_m W1[k][m]*sc[m]*W2[m][n]  (Bt layout, bf16) ----------
__global__ __launch_bounds__(256) void k_foldW(const float* __restrict__ W1,
                                               const float* __restrict__ W2,
                                               const float* __restrict__ sc,
                                               __hip_bfloat16* __restrict__ WfT) {
    int k = blockIdx.x;    // 0..127
    int n = threadIdx.x;   // 0..255
    float acc = 0.f;
    for (int m = 0; m < 256; m++) acc += W1[k * 256 + m] * sc[m] * W2[m * 256 + n];
    WfT[(size_t)n * 128 + k] = __float2bfloat16(acc);
}

// ---------- u[n] = sum_m W2[m][n] * bv[m] ----------
__global__ void k_uvec(const float* __restrict__ W2, const float* __restrict__ bv,
                       float* __restrict__ u) {
    int n = threadIdx.x;
    float acc = 0.f;
    for (int m = 0; m < 256; m++) acc += W2[m * 256 + n] * bv[m];
    u[n] = acc;
}

// ---------- wave-per-node pure-add SpMM on pre-scaled rows ----------
template <int PL>
static __device__ __forceinline__ void loadrow(const __hip_bfloat16* p, float* v) {
    if constexpr (PL == 4) {
        uint2 u = *(const uint2*)p;
        v[0] = bflo(u.x); v[1] = bfhi(u.x); v[2] = bflo(u.y); v[3] = bfhi(u.y);
    } else {
        unsigned u = *(const unsigned*)p;
        v[0] = bflo(u); v[1] = bfhi(u);
    }
}

template <int C>
__global__ __launch_bounds__(256) void k_spmm_w(const __hip_bfloat16* __restrict__ Hs,
                                                const int* __restrict__ rs,
                                                const int* __restrict__ rc,
                                                const int* __restrict__ col,
                                                const float* __restrict__ dinv,
                                                __hip_bfloat16* __restrict__ out,
                                                __hip_bfloat16* __restrict__ out2, int N) {
    constexpr int PL = C / 64;
    const int wid = blockIdx.x * 4 + (threadIdx.x >> 6);
    if (wid >= N) return;
    const int lane = threadIdx.x & 63;
    const int ch = lane * PL;
    const int s = rs[wid];
    const int deg = rc[wid];
    const float di = dinv[wid];

    float acc[PL];
    loadrow<PL>(Hs + (size_t)wid * C + ch, acc);  // self-loop term

    int e = 0;
    for (; e + 8 <= deg; e += 8) {
        int idx[8];
#pragma unroll
        for (int j = 0; j < 8; j++) idx[j] = col[s + e + j];
        float v[8][PL];
#pragma unroll
        for (int j = 0; j < 8; j++) loadrow<PL>(Hs + (size_t)idx[j] * C + ch, v[j]);
#pragma unroll
        for (int j = 0; j < 8; j++)
#pragma unroll
            for (int i = 0; i < PL; i++) acc[i] += v[j][i];
    }
    for (; e < deg; e++) {
        int i0 = col[s + e];
        float v0[PL];
        loadrow<PL>(Hs + (size_t)i0 * C + ch, v0);
#pragma unroll
        for (int i = 0; i < PL; i++) acc[i] += v0[i];
    }
    union { unsigned u[PL / 2]; unsigned short us[PL]; } o;
#pragma unroll
    for (int i = 0; i < PL; i++) {
        __hip_bfloat16 b = __float2bfloat16(di * acc[i]);
        o.us[i] = *(unsigned short*)&b;
    }
    if constexpr (PL == 4)
        *(uint2*)(out + (size_t)wid * C + ch) = *(uint2*)o.u;
    else
        *(unsigned*)(out + (size_t)wid * C + ch) = o.u[0];
    if (out2) {  // dinv-prescaled copy for the next aggregation pass
        union { unsigned u[PL / 2]; unsigned short us[PL]; } o2;
        float d2 = di * di;
#pragma unroll
        for (int i = 0; i < PL; i++) {
            __hip_bfloat16 b = __float2bfloat16(d2 * acc[i]);
            o2.us[i] = *(unsigned short*)&b;
        }
        if constexpr (PL == 4)
            *(uint2*)(out2 + (size_t)wid * C + ch) = *(uint2*)o2.u;
        else
            *(unsigned*)(out2 + (size_t)wid * C + ch) = o2.u[0];
    }
}

// ---------- chunked double-buffered MFMA GEMM, 128-row tile, 4 blocks/CU ----------
// out[M][256] = A[M][K] @ B[K][256] (+bias) (+ rank-1 rvec*uvec^T) ; optional BN affine on A;
// optional bf16/fp32 out; optional fused BN stats (atomics into NBIN replica bins).
// Block = 128 rows x 128 cols, grid (ceil(M/128), 2). K staged in 64-wide chunks,
// double-buffered LDS (36.9 KB -> 4 blocks/CU); A fragments ping-pong chunk-wise
// (~116 regs -> 4 waves/SIMD). Stage/load of chunk c+1 overlaps MFMA on chunk c.
// Stats arrays alias the (dead-by-then) B buffer.
// NOTE: last block reads A rows >= M (buffers padded by 128; results discarded by guard).
template <int K, bool STATS>
__global__ __launch_bounds__(256, 4) void k_gemm2(const __hip_bfloat16* __restrict__ A,
                                                  const __hip_bfloat16* __restrict__ Bt,
                                                  const float* __restrict__ bias,
                                                  __hip_bfloat16* __restrict__ outb,
                                                  float* __restrict__ outf,
                                                  float* __restrict__ gs,
                                                  const float* __restrict__ rvec,
                                                  const float* __restrict__ uvec,
                                                  const float* __restrict__ bnsc,
                                                  const float* __restrict__ bnof, int M) {
    constexpr int NC = K / 64;   // 64-wide K chunks
    constexpr int LDR = 72;      // chunk row stride (elems): +16B pad keeps bank spread
    __shared__ __align__(16) unsigned short Bs[2 * 128 * LDR];
    float* sred = (float*)Bs;        // aliases Bs: only touched after all MFMA reads + barrier
    float* qred = sred + 512;

    const int t = threadIdx.x;
    const int wv = t >> 6;
    const int lane = t & 63;
    const int mlane = lane & 15;
    const int quad = lane >> 4;
    const int m0 = blockIdx.x * 128;
    const int n0 = blockIdx.y * 128;
    const int arow0 = m0 + wv * 32 + mlane;  // mt adds +16

    // stage one 64-wide K chunk of the B slice into buf
    auto stage = [&](int c, int buf) {
#pragma unroll
        for (int i = 0; i < 4; i++) {  // 128 rows x 8 uint4 = 1024 / 256 threads
            int idx = t + i * 256;
            int row = idx >> 3;
            int c4 = idx & 7;
            uint4 v = *(const uint4*)(Bt + (size_t)(n0 + row) * K + c * 64 + c4 * 8);
            *(uint4*)(Bs + buf * (128 * LDR) + row * LDR + c4 * 8) = v;
        }
    };
    // load A fragments for chunk c (2 m-tiles x 2 k-steps), optional BN affine
    auto loadA = [&](int c, bf16x8 (&dst)[2][2]) {
#pragma unroll
        for (int mt = 0; mt < 2; mt++)
#pragma unroll
            for (int ks = 0; ks < 2; ks++) {
                int cb = c * 64 + ks * 32 + quad * 8;
                bf16x8 raw = *(const bf16x8*)(A + (size_t)(arow0 + mt * 16) * K + cb);
                if (bnsc) {
                    union { bf16x8 v; unsigned u[4]; } cu; cu.v = raw;
                    union { unsigned u[4]; unsigned short us[8]; } ou;
#pragma unroll
                    for (int j = 0; j < 4; j++) {
                        float lo = bflo(cu.u[j]) * bnsc[cb + 2 * j] + bnof[cb + 2 * j];
                        float hi = bfhi(cu.u[j]) * bnsc[cb + 2 * j + 1] + bnof[cb + 2 * j + 1];
                        __hip_bfloat16 bl = __float2bfloat16(lo);
                        __hip_bfloat16 bh = __float2bfloat16(hi);
                        ou.us[2 * j] = *(unsigned short*)&bl;
                        ou.us[2 * j + 1] = *(unsigned short*)&bh;
                    }
                    dst[mt][ks] = *(bf16x8*)ou.u;
                } else {
                    dst[mt][ks] = raw;
                }
            }
    };

    f32x4 acc[2][8];
#pragma unroll
    for (int mt = 0; mt < 2; mt++)
#pragma unroll
        for (int i = 0; i < 8; i++) acc[mt][i] = (f32x4){0.f, 0.f, 0.f, 0.f};

    bf16x8 aP[2][2], aQ[2][2];  // ping-pong A chunk fragments
    loadA(0, aP);
    stage(0, 0);

    auto mmachunk = [&](int c, bf16x8 (&ac)[2][2]) {
        const unsigned short* base = Bs + (c & 1) * (128 * LDR);
#pragma unroll
        for (int nt = 0; nt < 8; nt++) {
            const unsigned short* bp = base + (nt * 16 + mlane) * LDR + quad * 8;
#pragma unroll
            for (int ks = 0; ks < 2; ks++) {
                bf16x8 b = *(const bf16x8*)(bp + ks * 32);  // one LDS read, two MFMAs
                acc[0][nt] = __builtin_amdgcn_mfma_f32_16x16x32_bf16(ac[0][ks], b, acc[0][nt], 0, 0, 0);
                acc[1][nt] = __builtin_amdgcn_mfma_f32_16x16x32_bf16(ac[1][ks], b, acc[1][nt], 0, 0, 0);
            }
        }
    };

#pragma unroll
    for (int c = 0; c < NC; c++) {
        __syncthreads();  // buf[c&1] staged; previous reads of buf[(c+1)&1] done
        if (c + 1 < NC) {
            stage(c + 1, (c + 1) & 1);
            if ((c & 1) == 0) loadA(c + 1, aQ); else loadA(c + 1, aP);
        }
        if ((c & 1) == 0) mmachunk(c, aP); else mmachunk(c, aQ);
    }

    // C/D mapping: col = lane&15, row = quad*4 + reg
    float rv[2][4] = {{0.f, 0.f, 0.f, 0.f}, {0.f, 0.f, 0.f, 0.f}};
    if (rvec) {
#pragma unroll
        for (int mt = 0; mt < 2; mt++)
#pragma unroll
            for (int r = 0; r < 4; r++) {
                int row = m0 + wv * 32 + mt * 16 + quad * 4 + r;
                if (row < M) rv[mt][r] = rvec[row];
            }
    }
    float sp[8], qp[8];
#pragma unroll
    for (int nt = 0; nt < 8; nt++) {
        int colx = n0 + nt * 16 + mlane;
        float bv = bias[colx];
        float uvn = uvec ? uvec[colx] : 0.f;
        float s = 0.f, q = 0.f;
#pragma unroll
        for (int mt = 0; mt < 2; mt++)
#pragma unroll
            for (int r = 0; r < 4; r++) {
                int row = m0 + wv * 32 + mt * 16 + quad * 4 + r;
                if (row < M) {
                    float h = acc[mt][nt][r] + bv + rv[mt][r] * uvn;
                    if (outb) outb[(size_t)row * HID + colx] = __float2bfloat16(h);
                    if (outf) outf[(size_t)row * HID + colx] = h;
                    s += h;
                    q += h * h;
                }
            }
        sp[nt] = s;
        qp[nt] = q;
    }
    if constexpr (STATS) {
#pragma unroll
        for (int nt = 0; nt < 8; nt++) {
            sp[nt] += __shfl_xor(sp[nt], 16);
            sp[nt] += __shfl_xor(sp[nt], 32);
            qp[nt] += __shfl_xor(qp[nt], 16);
            qp[nt] += __shfl_xor(qp[nt], 32);
        }
        __syncthreads();  // all MFMA reads of Bs done -> safe to alias as sred/qred
        if (quad == 0) {
#pragma unroll
            for (int nt = 0; nt < 8; nt++) {
                sred[wv * 128 + nt * 16 + mlane] = sp[nt];
                qred[wv * 128 + nt * 16 + mlane] = qp[nt];
            }
        }
        __syncthreads();
        if (t < 128) {
            float ss = sred[t] + sred[128 + t] + sred[256 + t] + sred[384 + t];
            float qq = qred[t] + qred[128 + t] + qred[256 + t] + qred[384 + t];
            float* bin = gs + (blockIdx.x & (NBIN - 1)) * 512;  // de-contended replicas
            atomicAdd(&bin[n0 + t], ss);
            atomicAdd(&bin[256 + n0 + t], qq);
        }
    }
}

extern "C" void kernel_launch(void* const* d_in, const int* in_sizes, int n_in, void* d_out,
                              int out_size, void* d_ws, size_t ws_size, hipStream_t stream) {
    const float* x = (const float*)d_in[0];
    const int* ei = (const int*)d_in[1];
    const float* W1 = (const float*)d_in[2];
    const float* b1 = (const float*)d_in[3];
    const float* g1 = (const float*)d_in[4];
    const float* be1 = (const float*)d_in[5];
    const float* W2 = (const float*)d_in[6];
    const float* b2 = (const float*)d_in[7];
    const float* g2 = (const float*)d_in[8];
    const float* be2 = (const float*)d_in[9];
    const float* Wfc = (const float*)d_in[10];
    const float* bfc = (const float*)d_in[11];
    float* out = (float*)d_out;

    const int N = in_sizes[0] / NFEAT;  // 50000
    const int E = in_sizes[1] / 2;      // 800000
    const float invN = 1.0f / (float)N;

    char* ws = (char*)d_ws;
    size_t off = 0;
    auto alloc = [&](size_t bytes) -> void* {
        void* p = ws + off;
        off += (bytes + 255) & ~(size_t)255;
        return p;
    };
    int* row_cnt = (int*)alloc((size_t)N * 4);
    int* partial = (int*)alloc((size_t)N * 4);
    int* row_start = (int*)alloc((size_t)N * 4);
    int* blk = (int*)alloc(256 * 4);
    float* dinv = (float*)alloc((size_t)N * 4);
    int* rank = (int*)alloc((size_t)E * 4);
    int* col_idx = (int*)alloc((size_t)E * 4);
    float* gs1 = (float*)alloc((size_t)NBIN * 512 * 4);  // gs2 contiguous after
    float* gs2 = (float*)alloc((size_t)NBIN * 512 * 4);
    float* sc1 = (float*)alloc(256 * 4);
    float* bv1 = (float*)alloc(256 * 4);
    float* uvec = (float*)alloc(256 * 4);
    float* sc2 = (float*)alloc(256 * 4);
    float* of2 = (float*)alloc(256 * 4);
    float* rvec = (float*)alloc((size_t)(N + 128) * 4);
    __hip_bfloat16* Wt1 = (__hip_bfloat16*)alloc(256 * 128 * 2);
    __hip_bfloat16* Wtf = (__hip_bfloat16*)alloc(256 * 256 * 2);
    __hip_bfloat16* WfT = (__hip_bfloat16*)alloc(256 * 128 * 2);
    // node buffers padded by 128 rows (GEMM A-fragment overread of last 128-row block)
    __hip_bfloat16* xs = (__hip_bfloat16*)alloc((size_t)(N + 128) * NFEAT * 2);
    __hip_bfloat16* aggX = (__hip_bfloat16*)alloc((size_t)(N + 128) * NFEAT * 2);
    __hip_bfloat16* t1s = (__hip_bfloat16*)alloc((size_t)(N + 128) * NFEAT * 2);
    __hip_bfloat16* h2 = (__hip_bfloat16*)alloc((size_t)(N + 128) * HID * 2);
    __hip_bfloat16* t2 = xs;  // xs dead after spmm1

    hipMemsetAsync(row_cnt, 0, (size_t)N * 4, stream);
    hipMemsetAsync(gs1, 0, (size_t)NBIN * 512 * 4 * 2, stream);  // gs1 + gs2 (contiguous)

    // CSR build
    k_count<<<(E + 255) / 256, 256, 0, stream>>>(ei, E, row_cnt, rank);
    int nblk = (N + 255) / 256;
    k_scan1<<<nblk, 256, 0, stream>>>(row_cnt, N, partial, blk);
    k_scan2<<<1, 256, 0, stream>>>(blk, nblk);
    k_finalize<<<nblk, 256, 0, stream>>>(partial, blk, row_cnt, N, row_start, dinv);
    k_fill<<<(E + 255) / 256, 256, 0, stream>>>(ei, rank, row_start, E, col_idx);

    k_transpose2<<<384, 256, 0, stream>>>(W1, Wfc, Wt1, Wtf);

    // xs = dinv_row * x (bf16); shift = log2(128/4) = 5
    k_scale_cast<<<(N * NFEAT / 4 + 255) / 256, 256, 0, stream>>>(x, dinv, xs, 5, N * NFEAT / 4);

    int sg = (N + 3) / 4;
    k_rvec<<<sg, 256, 0, stream>>>(row_start, row_cnt, col_idx, dinv, rvec, N);

    dim3 gg((N + 127) / 128, 2);
    // t1 = A_hat * x : aggX (plain) + t1s (dinv-prescaled for pass 2)
    k_spmm_w<NFEAT><<<sg, 256, 0, stream>>>(xs, row_start, row_cnt, col_idx, dinv, aggX, t1s, N);
    // BN1 stats only: h1 = aggX@W1 + b1 (never materialized)
    k_gemm2<NFEAT, true><<<gg, 256, 0, stream>>>(aggX, Wt1, b1, nullptr, nullptr, gs1,
                                                 nullptr, nullptr, nullptr, nullptr, N);
    k_bnfold<<<1, 256, 0, stream>>>(gs1, g1, be1, b1, invN, sc1, bv1);
    k_foldW<<<128, 256, 0, stream>>>(W1, W2, sc1, WfT);
    k_uvec<<<1, 256, 0, stream>>>(W2, bv1, uvec);
    // t2 = A_hat * t1 (128-ch aggregation replaces the old 256-ch one)
    k_spmm_w<NFEAT><<<sg, 256, 0, stream>>>(t1s, row_start, row_cnt, col_idx, dinv, t2, nullptr, N);
    // h2pre = t2 @ (W1*diag(sc1)*W2) + rvec*uvec^T + b2, fused BN2 stats
    k_gemm2<NFEAT, true><<<gg, 256, 0, stream>>>(t2, WfT, b2, h2, nullptr, gs2,
                                                 rvec, uvec, nullptr, nullptr, N);
    k_bnfold<<<1, 256, 0, stream>>>(gs2, g2, be2, nullptr, invN, sc2, of2);
    // out = BN2(h2pre) @ Wfc + bfc ; BN2 affine folded into A-load
    k_gemm2<HID, false><<<gg, 256, 0, stream>>>(h2, Wtf, bfc, nullptr, out, nullptr,
                                                nullptr, nullptr, sc2, of2, N);
}

// Round 6
// 317.365 us; speedup vs baseline: 1.1853x; 1.0952x over previous
//
#include <hip/hip_runtime.h>
#include <hip/hip_bf16.h>

#define NFEAT 128
#define HID 256
#define BN_EPS 1e-5f
#define NBIN 64  // stats replica bins (atomic de-contention)

typedef __attribute__((ext_vector_type(8))) __bf16 bf16x8;
typedef __attribute__((ext_vector_type(4))) float f32x4;

static __device__ __forceinline__ float bflo(unsigned u) {
    union { unsigned x; float f; } c; c.x = u << 16; return c.f;
}
static __device__ __forceinline__ float bfhi(unsigned u) {
    union { unsigned x; float f; } c; c.x = u & 0xffff0000u; return c.f;
}

// ---------- CSR build ----------
__global__ void k_count(const int* __restrict__ ei, int E, int* __restrict__ cnt,
                        int* __restrict__ rank) {
    int e = blockIdx.x * blockDim.x + threadIdx.x;
    if (e < E) rank[e] = atomicAdd(&cnt[ei[E + e]], 1);
}

__global__ void k_scan1(const int* __restrict__ cnt, int n, int* __restrict__ partial,
                        int* __restrict__ blk_total) {
    __shared__ int sh[256];
    int i = blockIdx.x * 256 + threadIdx.x;
    int v = (i < n) ? cnt[i] : 0;
    sh[threadIdx.x] = v;
    __syncthreads();
    for (int off = 1; off < 256; off <<= 1) {
        int x = (threadIdx.x >= off) ? sh[threadIdx.x - off] : 0;
        __syncthreads();
        sh[threadIdx.x] += x;
        __syncthreads();
    }
    if (i < n) partial[i] = sh[threadIdx.x] - v;
    if (threadIdx.x == 255) blk_total[blockIdx.x] = sh[255];
}

// finalize with inline exclusive scan of blk_total (nblk <= 256): kills k_scan2
__global__ void k_finalize(const int* __restrict__ partial, const int* __restrict__ blk_total,
                           const int* __restrict__ cnt, int n, int nblk,
                           int* __restrict__ row_start, float* __restrict__ dinv) {
    __shared__ int sw[4];
    const int t = threadIdx.x;
    const int b = blockIdx.x;
    int v = (t < b && t < nblk) ? blk_total[t] : 0;
#pragma unroll
    for (int m = 1; m < 64; m <<= 1) v += __shfl_xor(v, m);
    if ((t & 63) == 0) sw[t >> 6] = v;
    __syncthreads();
    int pref = sw[0] + sw[1] + sw[2] + sw[3];
    int i = b * 256 + t;
    if (i < n) {
        row_start[i] = partial[i] + pref;
        dinv[i] = rsqrtf((float)(cnt[i] + 1));
    }
}

__global__ void k_fill(const int* __restrict__ ei, const int* __restrict__ rank,
                       const int* __restrict__ row_start, int E, int* __restrict__ col) {
    int e = blockIdx.x * blockDim.x + threadIdx.x;
    if (e < E) {
        int d = ei[E + e];
        col[row_start[d] + rank[e]] = ei[e];
    }
}

// ---------- fused: fp32->bf16 cast (dinv-scaled) + W1 transpose ----------
__global__ void k_prep(const float* __restrict__ x, const float* __restrict__ dinv,
                       __hip_bfloat16* __restrict__ xs, const float* __restrict__ W1,
                       __hip_bfloat16* __restrict__ Wt1, int castBlocks, int n4) {
    int bid = blockIdx.x;
    int t = threadIdx.x;
    if (bid < castBlocks) {
        int i = bid * 256 + t;
        if (i < n4) {
            float d = dinv[i >> 5];  // 32 4-elem groups per 128-ch row
            float4 v = *(const float4*)(x + (size_t)i * 4);
            __hip_bfloat16* o = xs + (size_t)i * 4;
            o[0] = __float2bfloat16(v.x * d);
            o[1] = __float2bfloat16(v.y * d);
            o[2] = __float2bfloat16(v.z * d);
            o[3] = __float2bfloat16(v.w * d);
        }
    } else {
        int idx = (bid - castBlocks) * 256 + t;  // 0..32767
        int n = idx & 255;
        int k = idx >> 8;  // 0..127
        Wt1[n * 128 + k] = __float2bfloat16(W1[k * 256 + n]);
    }
}

// ---------- merged BN1 fold + W-fold + uvec (one dispatch) ----------
// blocks 0..127: WfT[n][k=bid] = sum_m W1[bid][m]*sc[m]*W2[m][n]
// block 128:     uvec[n] = sum_m W2[m][n]*bv[m]
__global__ __launch_bounds__(256) void k_bnfoldW(const float* __restrict__ gs,
                                                 const float* __restrict__ g,
                                                 const float* __restrict__ be,
                                                 const float* __restrict__ b, float invN,
                                                 const float* __restrict__ W1,
                                                 const float* __restrict__ W2,
                                                 __hip_bfloat16* __restrict__ WfT,
                                                 float* __restrict__ uvec) {
    __shared__ float shs[256], shb[256];
    const int c = threadIdx.x;
    float s = 0.f, q = 0.f;
    for (int r = 0; r < NBIN; r++) {
        s += gs[r * 512 + c];
        q += gs[r * 512 + 256 + c];
    }
    float mean = s * invN;
    float var = q * invN - mean * mean;
    float scl = rsqrtf(var + BN_EPS) * g[c];
    shs[c] = scl;
    shb[c] = (b[c] - mean) * scl + be[c];
    __syncthreads();
    if (blockIdx.x < 128) {
        int k = blockIdx.x;
        float acc = 0.f;
        for (int m = 0; m < 256; m++) acc += W1[k * 256 + m] * shs[m] * W2[m * 256 + c];
        WfT[(size_t)c * 128 + k] = __float2bfloat16(acc);
    } else {
        float acc = 0.f;
        for (int m = 0; m < 256; m++) acc += W2[m * 256 + c] * shb[m];
        uvec[c] = acc;
    }
}

// ---------- BN2 folded into final-GEMM B + bias (one dispatch) ----------
// blocks 0..255 (k=bid): Wtf[n][k] = bf16(Wfc[k][n] * sc2[k])
// block 256: bias2[n] = bfc[n] + sum_m of2[m]*Wfc[m][n]
__global__ __launch_bounds__(256) void k_fold2(const float* __restrict__ gs,
                                               const float* __restrict__ g,
                                               const float* __restrict__ be, float invN,
                                               const float* __restrict__ Wfc,
                                               const float* __restrict__ bfc,
                                               __hip_bfloat16* __restrict__ Wtf,
                                               float* __restrict__ bias2) {
    __shared__ float shs[256], sho[256];
    const int c = threadIdx.x;
    float s = 0.f, q = 0.f;
    for (int r = 0; r < NBIN; r++) {
        s += gs[r * 512 + c];
        q += gs[r * 512 + 256 + c];
    }
    float mean = s * invN;
    float var = q * invN - mean * mean;
    float scl = rsqrtf(var + BN_EPS) * g[c];
    shs[c] = scl;
    sho[c] = (0.f - mean) * scl + be[c];
    __syncthreads();
    if (blockIdx.x < 256) {
        int k = blockIdx.x;
        Wtf[(size_t)c * 256 + k] = __float2bfloat16(Wfc[k * 256 + c] * shs[k]);
    } else {
        float acc = bfc[c];
        for (int m = 0; m < 256; m++) acc += sho[m] * Wfc[m * 256 + c];
        bias2[c] = acc;
    }
}

// ---------- wave-per-node SpMM (C=128), optional fused rvec / on-the-fly dj scale ----------
// SCALE=false (pass 1): gathers pre-scaled rows, acc += v; also rvec[i]=di*(di+sum dj).
// SCALE=true  (pass 2): gathers UNscaled T1 rows, acc += dj*v (dj broadcast from dinv).
template <bool SCALE>
__global__ __launch_bounds__(256) void k_spmm(const __hip_bfloat16* __restrict__ Hs,
                                              const int* __restrict__ rs,
                                              const int* __restrict__ rc,
                                              const int* __restrict__ col,
                                              const float* __restrict__ dinv,
                                              __hip_bfloat16* __restrict__ out,
                                              float* __restrict__ rv, int N) {
    const int wid = blockIdx.x * 4 + (threadIdx.x >> 6);
    if (wid >= N) return;
    const int lane = threadIdx.x & 63;
    const int ch = lane * 2;
    const int s = rs[wid];
    const int deg = rc[wid];
    const float di = dinv[wid];

    unsigned u0 = *(const unsigned*)(Hs + (size_t)wid * 128 + ch);  // self-loop
    float a0, a1, dsum = 0.f;
    if constexpr (SCALE) { a0 = di * bflo(u0); a1 = di * bfhi(u0); }
    else { a0 = bflo(u0); a1 = bfhi(u0); }

    int e = 0;
    for (; e + 8 <= deg; e += 8) {
        int idx[8];
#pragma unroll
        for (int j = 0; j < 8; j++) idx[j] = col[s + e + j];
        float dj[8];
#pragma unroll
        for (int j = 0; j < 8; j++) dj[j] = dinv[idx[j]];
        unsigned u[8];
#pragma unroll
        for (int j = 0; j < 8; j++) u[j] = *(const unsigned*)(Hs + (size_t)idx[j] * 128 + ch);
#pragma unroll
        for (int j = 0; j < 8; j++) {
            if constexpr (SCALE) { a0 += dj[j] * bflo(u[j]); a1 += dj[j] * bfhi(u[j]); }
            else { a0 += bflo(u[j]); a1 += bfhi(u[j]); dsum += dj[j]; }
        }
    }
    for (; e < deg; e++) {
        int i0 = col[s + e];
        float d0 = dinv[i0];
        unsigned uu = *(const unsigned*)(Hs + (size_t)i0 * 128 + ch);
        if constexpr (SCALE) { a0 += d0 * bflo(uu); a1 += d0 * bfhi(uu); }
        else { a0 += bflo(uu); a1 += bfhi(uu); dsum += d0; }
    }
    union { unsigned w; unsigned short us[2]; } o;
    __hip_bfloat16 b0 = __float2bfloat16(di * a0); o.us[0] = *(unsigned short*)&b0;
    __hip_bfloat16 b1 = __float2bfloat16(di * a1); o.us[1] = *(unsigned short*)&b1;
    *(unsigned*)(out + (size_t)wid * 128 + ch) = o.w;
    if (!SCALE && rv && lane == 0) rv[wid] = di * (di + dsum);
}

// ---------- chunked double-buffered MFMA GEMM, 128-row tile, 4 blocks/CU ----------
// out[M][256] = A[M][K] @ B[K][256] + bias (+ rank-1 rvec*uvec^T);
// optional bf16/fp32 out; optional fused BN stats (atomics into NBIN replica bins).
// Block = 128 rows x 128 cols, grid (ceil(M/128), 2). K staged in 64-wide chunks,
// double-buffered LDS; A fragments ping-pong chunk-wise. Stats alias dead B buffer.
// NOTE: last block reads A rows >= M (buffers padded by 128; results discarded by guard).
template <int K, bool STATS>
__global__ __launch_bounds__(256, 4) void k_gemm2(const __hip_bfloat16* __restrict__ A,
                                                  const __hip_bfloat16* __restrict__ Bt,
                                                  const float* __restrict__ bias,
                                                  __hip_bfloat16* __restrict__ outb,
                                                  float* __restrict__ outf,
                                                  float* __restrict__ gs,
                                                  const float* __restrict__ rvec,
                                                  const float* __restrict__ uvec, int M) {
    constexpr int NC = K / 64;   // 64-wide K chunks
    constexpr int LDR = 72;      // chunk row stride (elems): +16B pad keeps bank spread
    __shared__ __align__(16) unsigned short Bs[2 * 128 * LDR];
    float* sred = (float*)Bs;    // aliases Bs: only touched after all MFMA reads + barrier
    float* qred = sred + 512;

    const int t = threadIdx.x;
    const int wv = t >> 6;
    const int lane = t & 63;
    const int mlane = lane & 15;
    const int quad = lane >> 4;
    const int m0 = blockIdx.x * 128;
    const int n0 = blockIdx.y * 128;
    const int arow0 = m0 + wv * 32 + mlane;  // mt adds +16

    auto stage = [&](int c, int buf) {
#pragma unroll
        for (int i = 0; i < 4; i++) {  // 128 rows x 8 uint4 = 1024 / 256 threads
            int idx = t + i * 256;
            int row = idx >> 3;
            int c4 = idx & 7;
            uint4 v = *(const uint4*)(Bt + (size_t)(n0 + row) * K + c * 64 + c4 * 8);
            *(uint4*)(Bs + buf * (128 * LDR) + row * LDR + c4 * 8) = v;
        }
    };
    auto loadA = [&](int c, bf16x8 (&dst)[2][2]) {
#pragma unroll
        for (int mt = 0; mt < 2; mt++)
#pragma unroll
            for (int ks = 0; ks < 2; ks++)
                dst[mt][ks] = *(const bf16x8*)(A + (size_t)(arow0 + mt * 16) * K + c * 64 +
                                               ks * 32 + quad * 8);
    };

    f32x4 acc[2][8];
#pragma unroll
    for (int mt = 0; mt < 2; mt++)
#pragma unroll
        for (int i = 0; i < 8; i++) acc[mt][i] = (f32x4){0.f, 0.f, 0.f, 0.f};

    bf16x8 aP[2][2], aQ[2][2];  // ping-pong A chunk fragments
    loadA(0, aP);
    stage(0, 0);

    auto mmachunk = [&](int c, bf16x8 (&ac)[2][2]) {
        const unsigned short* base = Bs + (c & 1) * (128 * LDR);
#pragma unroll
        for (int nt = 0; nt < 8; nt++) {
            const unsigned short* bp = base + (nt * 16 + mlane) * LDR + quad * 8;
#pragma unroll
            for (int ks = 0; ks < 2; ks++) {
                bf16x8 b = *(const bf16x8*)(bp + ks * 32);  // one LDS read, two MFMAs
                acc[0][nt] = __builtin_amdgcn_mfma_f32_16x16x32_bf16(ac[0][ks], b, acc[0][nt], 0, 0, 0);
                acc[1][nt] = __builtin_amdgcn_mfma_f32_16x16x32_bf16(ac[1][ks], b, acc[1][nt], 0, 0, 0);
            }
        }
    };

#pragma unroll
    for (int c = 0; c < NC; c++) {
        __syncthreads();  // buf[c&1] staged; previous reads of buf[(c+1)&1] done
        if (c + 1 < NC) {
            stage(c + 1, (c + 1) & 1);
            if ((c & 1) == 0) loadA(c + 1, aQ); else loadA(c + 1, aP);
        }
        if ((c & 1) == 0) mmachunk(c, aP); else mmachunk(c, aQ);
    }

    // C/D mapping: col = lane&15, row = quad*4 + reg
    float rv[2][4] = {{0.f, 0.f, 0.f, 0.f}, {0.f, 0.f, 0.f, 0.f}};
    if (rvec) {
#pragma unroll
        for (int mt = 0; mt < 2; mt++)
#pragma unroll
            for (int r = 0; r < 4; r++) {
                int row = m0 + wv * 32 + mt * 16 + quad * 4 + r;
                if (row < M) rv[mt][r] = rvec[row];
            }
    }
    float sp[8], qp[8];
#pragma unroll
    for (int nt = 0; nt < 8; nt++) {
        int colx = n0 + nt * 16 + mlane;
        float bv = bias[colx];
        float uvn = uvec ? uvec[colx] : 0.f;
        float s = 0.f, q = 0.f;
#pragma unroll
        for (int mt = 0; mt < 2; mt++)
#pragma unroll
            for (int r = 0; r < 4; r++) {
                int row = m0 + wv * 32 + mt * 16 + quad * 4 + r;
                if (row < M) {
                    float h = acc[mt][nt][r] + bv + rv[mt][r] * uvn;
                    if (outb) outb[(size_t)row * HID + colx] = __float2bfloat16(h);
                    if (outf) outf[(size_t)row * HID + colx] = h;
                    s += h;
                    q += h * h;
                }
            }
        sp[nt] = s;
        qp[nt] = q;
    }
    if constexpr (STATS) {
#pragma unroll
        for (int nt = 0; nt < 8; nt++) {
            sp[nt] += __shfl_xor(sp[nt], 16);
            sp[nt] += __shfl_xor(sp[nt], 32);
            qp[nt] += __shfl_xor(qp[nt], 16);
            qp[nt] += __shfl_xor(qp[nt], 32);
        }
        __syncthreads();  // all MFMA reads of Bs done -> safe to alias as sred/qred
        if (quad == 0) {
#pragma unroll
            for (int nt = 0; nt < 8; nt++) {
                sred[wv * 128 + nt * 16 + mlane] = sp[nt];
                qred[wv * 128 + nt * 16 + mlane] = qp[nt];
            }
        }
        __syncthreads();
        if (t < 128) {
            float ss = sred[t] + sred[128 + t] + sred[256 + t] + sred[384 + t];
            float qq = qred[t] + qred[128 + t] + qred[256 + t] + qred[384 + t];
            float* bin = gs + (blockIdx.x & (NBIN - 1)) * 512;  // de-contended replicas
            atomicAdd(&bin[n0 + t], ss);
            atomicAdd(&bin[256 + n0 + t], qq);
        }
    }
}

extern "C" void kernel_launch(void* const* d_in, const int* in_sizes, int n_in, void* d_out,
                              int out_size, void* d_ws, size_t ws_size, hipStream_t stream) {
    const float* x = (const float*)d_in[0];
    const int* ei = (const int*)d_in[1];
    const float* W1 = (const float*)d_in[2];
    const float* b1 = (const float*)d_in[3];
    const float* g1 = (const float*)d_in[4];
    const float* be1 = (const float*)d_in[5];
    const float* W2 = (const float*)d_in[6];
    const float* b2 = (const float*)d_in[7];
    const float* g2 = (const float*)d_in[8];
    const float* be2 = (const float*)d_in[9];
    const float* Wfc = (const float*)d_in[10];
    const float* bfc = (const float*)d_in[11];
    float* out = (float*)d_out;

    const int N = in_sizes[0] / NFEAT;  // 50000
    const int E = in_sizes[1] / 2;      // 800000
    const float invN = 1.0f / (float)N;

    char* ws = (char*)d_ws;
    size_t off = 0;
    auto alloc = [&](size_t bytes) -> void* {
        void* p = ws + off;
        off += (bytes + 255) & ~(size_t)255;
        return p;
    };
    // row_cnt + gs1 + gs2 contiguous -> single memset
    int* row_cnt = (int*)alloc((size_t)N * 4);
    float* gs1 = (float*)alloc((size_t)NBIN * 512 * 4);
    float* gs2 = (float*)alloc((size_t)NBIN * 512 * 4);
    size_t zero_bytes = ((size_t)ws - (size_t)row_cnt) + off;  // == off (row_cnt at 0)
    int* partial = (int*)alloc((size_t)N * 4);
    int* row_start = (int*)alloc((size_t)N * 4);
    int* blk = (int*)alloc(256 * 4);
    float* dinv = (float*)alloc((size_t)N * 4);
    int* rank = (int*)alloc((size_t)E * 4);
    int* col_idx = (int*)alloc((size_t)E * 4);
    float* uvec = (float*)alloc(256 * 4);
    float* bias2 = (float*)alloc(256 * 4);
    float* rvec = (float*)alloc((size_t)(N + 128) * 4);
    __hip_bfloat16* Wt1 = (__hip_bfloat16*)alloc(256 * 128 * 2);
    __hip_bfloat16* Wtf = (__hip_bfloat16*)alloc(256 * 256 * 2);
    __hip_bfloat16* WfT = (__hip_bfloat16*)alloc(256 * 128 * 2);
    // node buffers padded by 128 rows (GEMM A-fragment overread of last 128-row block)
    __hip_bfloat16* xs = (__hip_bfloat16*)alloc((size_t)(N + 128) * NFEAT * 2);
    __hip_bfloat16* aggX = (__hip_bfloat16*)alloc((size_t)(N + 128) * NFEAT * 2);
    __hip_bfloat16* h2 = (__hip_bfloat16*)alloc((size_t)(N + 128) * HID * 2);
    __hip_bfloat16* t2 = xs;  // xs dead after spmm1

    hipMemsetAsync(row_cnt, 0, zero_bytes, stream);  // row_cnt + gs1 + gs2 in one fill

    // CSR build (4 dispatches: count, scan1, finalize(+scan2), fill)
    k_count<<<(E + 255) / 256, 256, 0, stream>>>(ei, E, row_cnt, rank);
    int nblk = (N + 255) / 256;
    k_scan1<<<nblk, 256, 0, stream>>>(row_cnt, N, partial, blk);
    k_finalize<<<nblk, 256, 0, stream>>>(partial, blk, row_cnt, N, nblk, row_start, dinv);
    k_fill<<<(E + 255) / 256, 256, 0, stream>>>(ei, rank, row_start, E, col_idx);

    // xs = dinv_row * x (bf16) + W1 transpose, one dispatch
    int castBlocks = (N * NFEAT / 4 + 255) / 256;
    k_prep<<<castBlocks + 128, 256, 0, stream>>>(x, dinv, xs, W1, Wt1, castBlocks, N * NFEAT / 4);

    int sg = (N + 3) / 4;
    dim3 gg((N + 127) / 128, 2);
    // t1 = A_hat * x (aggX) + fused rvec; then immediately t2 = A_hat * t1 (L2-warm aggX)
    k_spmm<false><<<sg, 256, 0, stream>>>(xs, row_start, row_cnt, col_idx, dinv, aggX, rvec, N);
    k_spmm<true><<<sg, 256, 0, stream>>>(aggX, row_start, row_cnt, col_idx, dinv, t2, nullptr, N);
    // BN1 stats only: h1 = aggX@W1 + b1 (never materialized)
    k_gemm2<NFEAT, true><<<gg, 256, 0, stream>>>(aggX, Wt1, b1, nullptr, nullptr, gs1,
                                                 nullptr, nullptr, N);
    // BN1 fold + WfT = W1*diag(sc1)*W2 + uvec, one dispatch
    k_bnfoldW<<<129, 256, 0, stream>>>(gs1, g1, be1, b1, invN, W1, W2, WfT, uvec);
    // h2pre = t2 @ WfT + rvec*uvec^T + b2, fused BN2 stats
    k_gemm2<NFEAT, true><<<gg, 256, 0, stream>>>(t2, WfT, b2, h2, nullptr, gs2,
                                                 rvec, uvec, N);
    // BN2 folded into B side: Wtf = diag(sc2)*Wfc (Bt layout), bias2 = of2^T Wfc + bfc
    k_fold2<<<257, 256, 0, stream>>>(gs2, g2, be2, invN, Wfc, bfc, Wtf, bias2);
    // out = h2 @ Wtf + bias2 (plain GEMM, fp32 out)
    k_gemm2<HID, false><<<gg, 256, 0, stream>>>(h2, Wtf, bias2, nullptr, out, nullptr,
                                                nullptr, nullptr, N);
}